// Round 5
// baseline (404.832 us; speedup 1.0000x reference)
//
#include <hip/hip_runtime.h>
#include <math.h>

// n=16384 Gaussian points in 3D. Exact 12-NN (incl self) per point:
//   out[i] = b + ( (W·p_i)·(1 + 11/sqrt(2)) + 0.5 * sum_{11NN} W·|p_i - p_j| ) / 12
//
// R5: ONE single-block counting-sort kernel (LDS hist+scan+scatter, x-bins),
// then ONE query kernel: 512 blocks x 256 thr, 32 consecutive sorted queries
// per block, FIXED 3072-position window centered on the block (clamped inward;
// sized ~1.7x the worst-case needed center window ~1800). Uniform control flow:
// stage window once into LDS (36KB, resident), R1-style branch-free med3
// top-12 over it, ONE exact 8-way merge -> tau, per-query exactness check
// ((x-gap - binwidth)^2 > tau at both window edges). If ANY query in a block
// fails (expected never), the whole block uniformly redoes full brute force.
// Phase 2 rescans the resident LDS window with exact tau; self contributes 0.

#define NBINS   2048
#define XMIN_   (-6.0f)
#define XRANGE_ (12.0f)
#define BW_     (XRANGE_ / (float)NBINS)
#define INVBW_  ((float)NBINS / XRANGE_)
#define SLACK_  (BW_ * 1.02f)
#define WIN     3072
#define GRP     (WIN / 4)
#define GL      8
#define QPB     32
#define BLOCK   256
#define KK      12
#define KP      13
#define BIG     3.0e38f
#define PADX    1.0e30f

__device__ __forceinline__ int bin_of(float x) {
  int b = (int)((x - XMIN_) * INVBW_);
  b = b < 0 ? 0 : b;
  b = b > NBINS - 1 ? NBINS - 1 : b;
  return b;
}

// ---------------- K1: fused counting sort (single block) ---------------------
__global__ __launch_bounds__(1024)
void sort_kernel(const float* __restrict__ p, float4* __restrict__ sorted, int n) {
  __shared__ int h[NBINS];
  __shared__ int ssum[1024];
  const int tid = threadIdx.x;

  h[tid] = 0; h[tid + 1024] = 0;
  __syncthreads();

  const int ppt = (n + 1023) / 1024;   // 16
  for (int k = 0; k < ppt; ++k) {
    const int i = tid * ppt + k;
    if (i < n) atomicAdd(&h[bin_of(p[3 * i])], 1);
  }
  __syncthreads();

  const int a = h[2 * tid], b = h[2 * tid + 1];
  ssum[tid] = a + b;
  __syncthreads();
  for (int off = 1; off < 1024; off <<= 1) {
    const int v = (tid >= off) ? ssum[tid - off] : 0;
    __syncthreads();
    ssum[tid] += v;
    __syncthreads();
  }
  const int excl = ssum[tid] - (a + b);
  __syncthreads();
  h[2 * tid]     = excl;
  h[2 * tid + 1] = excl + a;
  __syncthreads();

  for (int k = 0; k < ppt; ++k) {
    const int i = tid * ppt + k;
    if (i < n) {
      const float x = p[3 * i], y = p[3 * i + 1], z = p[3 * i + 2];
      const int pos = atomicAdd(&h[bin_of(x)], 1);
      sorted[pos] = make_float4(x, y, z, __int_as_float(i));
    }
  }
}

// ---------------- K2: query ----------------------------------------------------
__global__ __launch_bounds__(BLOCK)
void query_kernel(const float4* __restrict__ sv, const float* __restrict__ W,
                  const float* __restrict__ bias, float* __restrict__ out, int n) {
  __shared__ __align__(16) float s_x[WIN];
  __shared__ __align__(16) float s_y[WIN];
  __shared__ __align__(16) float s_z[WIN];
  __shared__ float s_d[BLOCK * KP];
  __shared__ float s_tau[QPB];
  __shared__ int   s_fail;

  const int tid = threadIdx.x;
  const int sl  = tid & (GL - 1);
  const int ql  = tid >> 3;
  const int c   = blockIdx.x * QPB;
  const int t   = c + ql;

  int lo = c + QPB / 2 - WIN / 2;
  lo = lo < 0 ? 0 : lo;
  lo = lo > n - WIN ? n - WIN : lo;

  const float4 me = sv[t];
  const float xi = me.x, yi = me.y, zi = me.z;
  const int orig = __float_as_int(me.w);

  // ---- stage fixed window (all positions valid, no bounds checks) ----
#pragma unroll
  for (int j0 = 0; j0 < WIN; j0 += BLOCK) {
    const int j = j0 + tid;
    const float4 cc = sv[lo + j];
    s_x[j] = cc.x; s_y[j] = cc.y; s_z[j] = cc.z;
  }
  __syncthreads();

  float dist[KK];
#pragma unroll
  for (int k = 0; k < KK; ++k) dist[k] = BIG;

  // ---- phase 1: branch-free med3 top-12 over resident window ----
#pragma unroll 2
  for (int g = sl; g < GRP; g += GL) {
    const int cb = g * 4;
    const float4 X = *(const float4*)&s_x[cb];
    const float4 Y = *(const float4*)&s_y[cb];
    const float4 Z = *(const float4*)&s_z[cb];
    float d2v[4];
    { const float dx = xi - X.x, dy = yi - Y.x, dz = zi - Z.x; d2v[0] = dx*dx + dy*dy + dz*dz; }
    { const float dx = xi - X.y, dy = yi - Y.y, dz = zi - Z.y; d2v[1] = dx*dx + dy*dy + dz*dz; }
    { const float dx = xi - X.z, dy = yi - Y.z, dz = zi - Z.z; d2v[2] = dx*dx + dy*dy + dz*dz; }
    { const float dx = xi - X.w, dy = yi - Y.w, dz = zi - Z.w; d2v[3] = dx*dx + dy*dy + dz*dz; }
#pragma unroll
    for (int e = 0; e < 4; ++e) {
      const float d = d2v[e];
#pragma unroll
      for (int k = KK - 1; k >= 1; --k)
        dist[k] = __builtin_amdgcn_fmed3f(d, dist[k - 1], dist[k]);
      dist[0] = fminf(dist[0], d);
    }
  }

  // ---- exact tau: 8-way merge of sorted per-slice lists ----
  __syncthreads();
#pragma unroll
  for (int k = 0; k < KK; ++k) s_d[tid * KP + k] = dist[k];
  if (tid == 0) s_fail = 0;
  __syncthreads();
  if (sl == 0) {
    int hh[GL];
#pragma unroll
    for (int g = 0; g < GL; ++g) hh[g] = 0;
    float tau = 0.f;
    for (int r = 0; r < KK; ++r) {
      float best = 3.4e38f; int bs = 0;
#pragma unroll
      for (int g = 0; g < GL; ++g) {
        const float v = s_d[(tid + g) * KP + hh[g]];
        if (v < best) { best = v; bs = g; }
      }
#pragma unroll
      for (int g = 0; g < GL; ++g) hh[g] += (bs == g) ? 1 : 0;
      tau = best;
    }
    s_tau[ql] = tau;
    // exactness check vs window edges (bin-sort: unstaged x beyond edge +/- BW)
    bool okL = (lo == 0);
    if (!okL) { const float gp = xi - s_x[0] - SLACK_; okL = (gp > 0.f) && (gp * gp > tau); }
    bool okR = (lo + WIN >= n);
    if (!okR) { const float gp = s_x[WIN - 1] - SLACK_ - xi; okR = (gp > 0.f) && (gp * gp > tau); }
    if (!(okL && okR)) atomicOr(&s_fail, 1);
  }
  __syncthreads();

  float tau = s_tau[ql];
  const float W0 = W[0], W1 = W[1], W2 = W[2];
  float acc = 0.f;

  if (!s_fail) {
    // ---- fast phase 2: rescan resident LDS window ----
#pragma unroll 2
    for (int g = sl; g < GRP; g += GL) {
      const int cb = g * 4;
      const float4 X = *(const float4*)&s_x[cb];
      const float4 Y = *(const float4*)&s_y[cb];
      const float4 Z = *(const float4*)&s_z[cb];
      { const float dx = xi - X.x, dy = yi - Y.x, dz = zi - Z.x;
        acc += (dx*dx + dy*dy + dz*dz <= tau) ? (W0*fabsf(dx) + W1*fabsf(dy) + W2*fabsf(dz)) : 0.f; }
      { const float dx = xi - X.y, dy = yi - Y.y, dz = zi - Z.y;
        acc += (dx*dx + dy*dy + dz*dz <= tau) ? (W0*fabsf(dx) + W1*fabsf(dy) + W2*fabsf(dz)) : 0.f; }
      { const float dx = xi - X.z, dy = yi - Y.z, dz = zi - Z.z;
        acc += (dx*dx + dy*dy + dz*dz <= tau) ? (W0*fabsf(dx) + W1*fabsf(dy) + W2*fabsf(dz)) : 0.f; }
      { const float dx = xi - X.w, dy = yi - Y.w, dz = zi - Z.w;
        acc += (dx*dx + dy*dy + dz*dz <= tau) ? (W0*fabsf(dx) + W1*fabsf(dy) + W2*fabsf(dz)) : 0.f; }
    }
  } else {
    // ---- rare exact fallback: whole block brute-forces the full array ----
#pragma unroll
    for (int k = 0; k < KK; ++k) dist[k] = BIG;
    for (int base = 0; base < n; base += WIN) {
      __syncthreads();
#pragma unroll
      for (int j0 = 0; j0 < WIN; j0 += BLOCK) {
        const int j = j0 + tid;
        const int pos = base + j;
        const float4 cc = (pos < n) ? sv[pos] : make_float4(PADX, PADX, PADX, 0.f);
        s_x[j] = cc.x; s_y[j] = cc.y; s_z[j] = cc.z;
      }
      __syncthreads();
      for (int g = sl; g < GRP; g += GL) {
        const int cb = g * 4;
        const float4 X = *(const float4*)&s_x[cb];
        const float4 Y = *(const float4*)&s_y[cb];
        const float4 Z = *(const float4*)&s_z[cb];
        float d2v[4];
        { const float dx = xi - X.x, dy = yi - Y.x, dz = zi - Z.x; d2v[0] = dx*dx + dy*dy + dz*dz; }
        { const float dx = xi - X.y, dy = yi - Y.y, dz = zi - Z.y; d2v[1] = dx*dx + dy*dy + dz*dz; }
        { const float dx = xi - X.z, dy = yi - Y.z, dz = zi - Z.z; d2v[2] = dx*dx + dy*dy + dz*dz; }
        { const float dx = xi - X.w, dy = yi - Y.w, dz = zi - Z.w; d2v[3] = dx*dx + dy*dy + dz*dz; }
#pragma unroll
        for (int e = 0; e < 4; ++e) {
          const float d = d2v[e];
#pragma unroll
          for (int k = KK - 1; k >= 1; --k)
            dist[k] = __builtin_amdgcn_fmed3f(d, dist[k - 1], dist[k]);
          dist[0] = fminf(dist[0], d);
        }
      }
    }
    __syncthreads();
#pragma unroll
    for (int k = 0; k < KK; ++k) s_d[tid * KP + k] = dist[k];
    __syncthreads();
    if (sl == 0) {
      int hh[GL];
#pragma unroll
      for (int g = 0; g < GL; ++g) hh[g] = 0;
      float tf = 0.f;
      for (int r = 0; r < KK; ++r) {
        float best = 3.4e38f; int bs = 0;
#pragma unroll
        for (int g = 0; g < GL; ++g) {
          const float v = s_d[(tid + g) * KP + hh[g]];
          if (v < best) { best = v; bs = g; }
        }
#pragma unroll
        for (int g = 0; g < GL; ++g) hh[g] += (bs == g) ? 1 : 0;
        tf = best;
      }
      s_tau[ql] = tf;
    }
    __syncthreads();
    tau = s_tau[ql];
    for (int base = 0; base < n; base += WIN) {
      __syncthreads();
#pragma unroll
      for (int j0 = 0; j0 < WIN; j0 += BLOCK) {
        const int j = j0 + tid;
        const int pos = base + j;
        const float4 cc = (pos < n) ? sv[pos] : make_float4(PADX, PADX, PADX, 0.f);
        s_x[j] = cc.x; s_y[j] = cc.y; s_z[j] = cc.z;
      }
      __syncthreads();
      for (int g = sl; g < GRP; g += GL) {
        const int cb = g * 4;
        const float4 X = *(const float4*)&s_x[cb];
        const float4 Y = *(const float4*)&s_y[cb];
        const float4 Z = *(const float4*)&s_z[cb];
        { const float dx = xi - X.x, dy = yi - Y.x, dz = zi - Z.x;
          acc += (dx*dx + dy*dy + dz*dz <= tau) ? (W0*fabsf(dx) + W1*fabsf(dy) + W2*fabsf(dz)) : 0.f; }
        { const float dx = xi - X.y, dy = yi - Y.y, dz = zi - Z.y;
          acc += (dx*dx + dy*dy + dz*dz <= tau) ? (W0*fabsf(dx) + W1*fabsf(dy) + W2*fabsf(dz)) : 0.f; }
        { const float dx = xi - X.z, dy = yi - Y.z, dz = zi - Z.z;
          acc += (dx*dx + dy*dy + dz*dz <= tau) ? (W0*fabsf(dx) + W1*fabsf(dy) + W2*fabsf(dz)) : 0.f; }
        { const float dx = xi - X.w, dy = yi - Y.w, dz = zi - Z.w;
          acc += (dx*dx + dy*dy + dz*dz <= tau) ? (W0*fabsf(dx) + W1*fabsf(dy) + W2*fabsf(dz)) : 0.f; }
      }
    }
  }

  // ---- reduce over the 8 slice lanes, leader writes ----
  acc += __shfl_xor(acc, 1);
  acc += __shfl_xor(acc, 2);
  acc += __shfl_xor(acc, 4);
  if (sl == 0) {
    const float xw0 = W0 * xi + W1 * yi + W2 * zi;
    out[orig] = bias[0] + (xw0 * 8.778174593052022f + 0.5f * acc) * (1.0f / 12.0f);
  }
}

extern "C" void kernel_launch(void* const* d_in, const int* in_sizes, int n_in,
                              void* d_out, int out_size, void* d_ws, size_t ws_size,
                              hipStream_t stream) {
  const float* p  = (const float*)d_in[0];
  const float* W  = (const float*)d_in[1];
  const float* bb = (const float*)d_in[2];
  float* out = (float*)d_out;

  const int n = in_sizes[0] / 3;   // 16384
  float4* sorted = (float4*)d_ws;  // 16n bytes

  sort_kernel<<<1, 1024, 0, stream>>>(p, sorted, n);
  query_kernel<<<n / QPB, BLOCK, 0, stream>>>(sorted, W, bb, out, n);
}

// Round 6
// 315.591 us; speedup vs baseline: 1.2828x; 1.2828x over previous
//
#include <hip/hip_runtime.h>
#include <math.h>

// n=16384 Gaussian points in 3D. Exact 12-NN (incl self) per point:
//   out[i] = b + ( (W·p_i)·(1 + 11/sqrt(2)) + 0.5 * sum_{11NN} W·|p_i - p_j| ) / 12
//
// R6: no windows, no fallback. S1: per-query tau_ub (exact 12th of a sorted
// 1024-ring — ANY >=12 subset gives a valid upper bound, so sort quality only
// affects speed, never correctness). S2: exhaustive scan of all n candidates,
// ~8 inst/pair (distance + compare vs min(tau_ub, running-12th)); the ~15-40
// passing candidates per query take a rare exec-masked payload (d2, W·|diff|)
// sorted insert. Merge of payload lists -> exact tau; per-lane masked sum of
// payloads <= tau -> answer. Unconditionally exact: a skipped candidate is
// larger than 12 other candidates, so it cannot be a true 12-NN.
// Sort = ONE dispatch: 64 co-resident blocks + device-atomic spin barriers.

#define NBINS  2048
#define XMIN_  (-6.0f)
#define INVBW_ ((float)NBINS / 12.0f)
#define SORTB  64
#define STHR   256
#define QPB    32
#define BLOCK  256
#define GL     8
#define RING   1024
#define CHUNK  2048
#define KK     12
#define KP     13
#define BIG    3.0e38f
#define PADX   1.0e30f

__device__ __forceinline__ int bin_of(float x) {
  int b = (int)((x - XMIN_) * INVBW_);
  b = b < 0 ? 0 : b;
  b = b > NBINS - 1 ? NBINS - 1 : b;
  return b;
}

// device-scope spin barrier; safe: 64 tiny blocks are trivially co-resident
__device__ __forceinline__ void gbar(int* c, int target) {
  __syncthreads();
  if (threadIdx.x == 0) {
    __threadfence();
    atomicAdd(c, 1);
    while (atomicAdd(c, 0) < target) __builtin_amdgcn_s_sleep(2);
    __threadfence();
  }
  __syncthreads();
}

// ---------------- K1: fused counting sort (hist | scan | scatter) ------------
__global__ __launch_bounds__(STHR)
void sort_kernel(const float* __restrict__ p, int* __restrict__ hist,
                 int* __restrict__ cursor, int* __restrict__ cnt,
                 float4* __restrict__ sorted, int n) {
  __shared__ int ssum[STHR];
  const int tid = threadIdx.x;
  const int gid = blockIdx.x * STHR + tid;

  for (int i = gid; i < n; i += SORTB * STHR)
    atomicAdd(&hist[bin_of(p[3 * i])], 1);

  gbar(&cnt[0], SORTB);

  if (blockIdx.x == 0) {
    const int base = tid * (NBINS / STHR);
    int v[NBINS / STHR];
    int sum = 0;
#pragma unroll
    for (int t = 0; t < NBINS / STHR; ++t) { v[t] = hist[base + t]; sum += v[t]; }
    ssum[tid] = sum;
    __syncthreads();
    for (int off = 1; off < STHR; off <<= 1) {
      const int x = (tid >= off) ? ssum[tid - off] : 0;
      __syncthreads();
      ssum[tid] += x;
      __syncthreads();
    }
    int run = (tid > 0) ? ssum[tid - 1] : 0;
#pragma unroll
    for (int t = 0; t < NBINS / STHR; ++t) { cursor[base + t] = run; run += v[t]; }
  }

  gbar(&cnt[1], SORTB);

  for (int i = gid; i < n; i += SORTB * STHR) {
    const float x = p[3 * i], y = p[3 * i + 1], z = p[3 * i + 2];
    const int pos = atomicAdd(&cursor[bin_of(x)], 1);
    sorted[pos] = make_float4(x, y, z, __int_as_float(i));
  }
}

// ---------------- K2: query ---------------------------------------------------
__global__ __launch_bounds__(BLOCK)
void query_kernel(const float4* __restrict__ sv, const float* __restrict__ W,
                  const float* __restrict__ bias, float* __restrict__ out, int n) {
  __shared__ __align__(16) float s_x[CHUNK];
  __shared__ __align__(16) float s_y[CHUNK];
  __shared__ __align__(16) float s_z[CHUNK];
  __shared__ float s_d[BLOCK * KP];
  __shared__ float s_tub[QPB];
  __shared__ float s_tau[QPB];

  const int tid = threadIdx.x;
  const int sl  = tid & (GL - 1);
  const int ql  = tid >> 3;
  const int t   = blockIdx.x * QPB + ql;

  const float4 me = sv[t];
  const float xi = me.x, yi = me.y, zi = me.z;
  const int orig = __float_as_int(me.w);
  const float W0 = W[0], W1 = W[1], W2 = W[2];

  float qd[KK], qw[KK];
#pragma unroll
  for (int k = 0; k < KK; ++k) qd[k] = BIG;

  // ======== S1: tau_ub from a 1024-ring of sorted positions ========
  int rlo = blockIdx.x * QPB + QPB / 2 - RING / 2;
  rlo = rlo < 0 ? 0 : (rlo > n - RING ? n - RING : rlo);

#pragma unroll
  for (int j0 = 0; j0 < RING; j0 += BLOCK) {
    const int j = j0 + tid;
    const float4 cc = sv[rlo + j];
    s_x[j] = cc.x; s_y[j] = cc.y; s_z[j] = cc.z;
  }
  __syncthreads();

#pragma unroll 2
  for (int g = sl; g < RING / 4; g += GL) {
    const int cb = g * 4;
    const float4 X = *(const float4*)&s_x[cb];
    const float4 Y = *(const float4*)&s_y[cb];
    const float4 Z = *(const float4*)&s_z[cb];
    float d2v[4];
    { const float dx = xi - X.x, dy = yi - Y.x, dz = zi - Z.x; d2v[0] = dx*dx + dy*dy + dz*dz; }
    { const float dx = xi - X.y, dy = yi - Y.y, dz = zi - Z.y; d2v[1] = dx*dx + dy*dy + dz*dz; }
    { const float dx = xi - X.z, dy = yi - Y.z, dz = zi - Z.z; d2v[2] = dx*dx + dy*dy + dz*dz; }
    { const float dx = xi - X.w, dy = yi - Y.w, dz = zi - Z.w; d2v[3] = dx*dx + dy*dy + dz*dz; }
#pragma unroll
    for (int e = 0; e < 4; ++e) {
      const float d = d2v[e];
#pragma unroll
      for (int k = KK - 1; k >= 1; --k)
        qd[k] = __builtin_amdgcn_fmed3f(d, qd[k - 1], qd[k]);
      qd[0] = fminf(qd[0], d);
    }
  }

  __syncthreads();
#pragma unroll
  for (int k = 0; k < KK; ++k) s_d[tid * KP + k] = qd[k];
  __syncthreads();
  if (sl == 0) {
    int h[GL];
#pragma unroll
    for (int g = 0; g < GL; ++g) h[g] = 0;
    float tt = 0.f;
    for (int r = 0; r < KK; ++r) {
      float best = 3.4e38f; int bs = 0;
#pragma unroll
      for (int g = 0; g < GL; ++g) {
        const float v = s_d[(tid + g) * KP + h[g]];
        if (v < best) { best = v; bs = g; }
      }
#pragma unroll
      for (int g = 0; g < GL; ++g) h[g] += (bs == g) ? 1 : 0;
      tt = best;
    }
    s_tub[ql] = tt;
  }
  __syncthreads();
  const float tub = s_tub[ql];

  // ======== S2: exhaustive filtered scan with payload top-12 ========
#pragma unroll
  for (int k = 0; k < KK; ++k) { qd[k] = BIG; qw[k] = 0.f; }

  for (int base = 0; base < n; base += CHUNK) {
    __syncthreads();
#pragma unroll
    for (int j0 = 0; j0 < CHUNK; j0 += BLOCK) {
      const int j = j0 + tid;
      const int pos = base + j;
      const float4 cc = (pos < n) ? sv[pos] : make_float4(PADX, PADX, PADX, 0.f);
      s_x[j] = cc.x; s_y[j] = cc.y; s_z[j] = cc.z;
    }
    __syncthreads();

#pragma unroll 2
    for (int g = sl; g < CHUNK / 4; g += GL) {
      const int cb = g * 4;
      const float4 X = *(const float4*)&s_x[cb];
      const float4 Y = *(const float4*)&s_y[cb];
      const float4 Z = *(const float4*)&s_z[cb];
      float d2v[4];
      { const float dx = xi - X.x, dy = yi - Y.x, dz = zi - Z.x; d2v[0] = dx*dx + dy*dy + dz*dz; }
      { const float dx = xi - X.y, dy = yi - Y.y, dz = zi - Z.y; d2v[1] = dx*dx + dy*dy + dz*dz; }
      { const float dx = xi - X.z, dy = yi - Y.z, dz = zi - Z.z; d2v[2] = dx*dx + dy*dy + dz*dz; }
      { const float dx = xi - X.w, dy = yi - Y.w, dz = zi - Z.w; d2v[3] = dx*dx + dy*dy + dz*dz; }

      const float thr = fminf(tub, qd[KK - 1]);
      const float m4 = fminf(fminf(d2v[0], d2v[1]), fminf(d2v[2], d2v[3]));
      if (m4 <= thr) {
        // rare path: payload sorted insert for each passing candidate
#pragma unroll
        for (int e = 0; e < 4; ++e) {
          const float d = d2v[e];
          if (d <= thr) {
            const float cx = (e == 0) ? X.x : (e == 1) ? X.y : (e == 2) ? X.z : X.w;
            const float cy = (e == 0) ? Y.x : (e == 1) ? Y.y : (e == 2) ? Y.z : Y.w;
            const float cz = (e == 0) ? Z.x : (e == 1) ? Z.y : (e == 2) ? Z.z : Z.w;
            const float w = fmaf(W0, fabsf(xi - cx),
                            fmaf(W1, fabsf(yi - cy), W2 * fabsf(zi - cz)));
#pragma unroll
            for (int k = KK - 1; k >= 1; --k) {
              const bool up = (qd[k - 1] > d);
              const float nd = up ? qd[k - 1] : ((qd[k] > d) ? d : qd[k]);
              const float nw = up ? qw[k - 1] : ((qd[k] > d) ? w : qw[k]);
              qd[k] = nd; qw[k] = nw;
            }
            if (qd[0] > d) { qw[0] = w; qd[0] = d; }
          }
        }
      }
    }
  }

  // ======== merge payload lists -> exact tau; masked sum ========
  __syncthreads();
#pragma unroll
  for (int k = 0; k < KK; ++k) s_d[tid * KP + k] = qd[k];
  __syncthreads();
  if (sl == 0) {
    int h[GL];
#pragma unroll
    for (int g = 0; g < GL; ++g) h[g] = 0;
    float tt = 0.f;
    for (int r = 0; r < KK; ++r) {
      float best = 3.4e38f; int bs = 0;
#pragma unroll
      for (int g = 0; g < GL; ++g) {
        const float v = s_d[(tid + g) * KP + h[g]];
        if (v < best) { best = v; bs = g; }
      }
#pragma unroll
      for (int g = 0; g < GL; ++g) h[g] += (bs == g) ? 1 : 0;
      tt = best;
    }
    s_tau[ql] = tt;
  }
  __syncthreads();
  const float tau = s_tau[ql];

  float acc = 0.f;
#pragma unroll
  for (int k = 0; k < KK; ++k) acc += (qd[k] <= tau) ? qw[k] : 0.f;
  acc += __shfl_xor(acc, 1);
  acc += __shfl_xor(acc, 2);
  acc += __shfl_xor(acc, 4);

  if (sl == 0) {
    const float xw0 = W0 * xi + W1 * yi + W2 * zi;
    // 1 + 11/sqrt(2)
    out[orig] = bias[0] + (xw0 * 8.778174593052022f + 0.5f * acc) * (1.0f / 12.0f);
  }
}

extern "C" void kernel_launch(void* const* d_in, const int* in_sizes, int n_in,
                              void* d_out, int out_size, void* d_ws, size_t ws_size,
                              hipStream_t stream) {
  const float* p  = (const float*)d_in[0];
  const float* W  = (const float*)d_in[1];
  const float* bb = (const float*)d_in[2];
  float* out = (float*)d_out;

  const int n = in_sizes[0] / 3;   // 16384

  // ws layout: hist[2048] @0 | cnt[2] @8192 | cursor[2048] @8256 | sorted @16448
  int*    hist   = (int*)d_ws;
  int*    cnt    = (int*)((char*)d_ws + 8192);
  int*    cursor = (int*)((char*)d_ws + 8256);
  float4* sorted = (float4*)((char*)d_ws + 16448);

  hipMemsetAsync(d_ws, 0, 8256, stream);   // hist + cnt
  sort_kernel<<<SORTB, STHR, 0, stream>>>(p, hist, cursor, cnt, sorted, n);
  query_kernel<<<n / QPB, BLOCK, 0, stream>>>(sorted, W, bb, out, n);
}

// Round 7
// 228.471 us; speedup vs baseline: 1.7719x; 1.3813x over previous
//
#include <hip/hip_runtime.h>
#include <math.h>

// n=16384 Gaussian points in 3D. Exact 12-NN (incl self) per point:
//   out[i] = b + ( (W·p_i)·(1 + 11/sqrt(2)) + 0.5 * sum_{11NN} W·|p_i - p_j| ) / 12
//
// R7: x-bin counting sort (1 fused dispatch). Query: 1024 blocks x 256 thr;
// 16 consecutive sorted queries/block x 16 slices (GL=16 -> 4096 waves,
// 4/SIMD). Sorted array viewed as 16 chunks of 1024. Per block:
//   seed chunk (contains the block's queries) -> branchless med3 top-12 ->
//   merge -> tau_ub. Then every other chunk: BLOCK-UNIFORM skip test
//   ((x-gap - binwidth)^2 > max_q tau_ub) else stage+branchless insert.
//   Merge -> exact tau. Scan B: same uniform chunk skip vs max_q tau,
//   branchless masked accumulate of W·|diff| for d2 <= tau (self adds 0).
// Exact: skipped chunks provably contain no top-12 member of any block query;
// non-skipped chunks are fully inserted; per-lane med3 lists are exact top-12
// of what the lane saw; 16-way merge is exact.

#define NBINS  2048
#define XMIN_  (-6.0f)
#define INVBW_ ((float)NBINS / 12.0f)
#define BWS_   ((12.0f / (float)NBINS) * 1.02f)
#define SORTB  64
#define STHR   256
#define QPB    16
#define GL     16
#define BLOCK  256
#define CHUNK  1024
#define MAXCHK 32
#define KK     12
#define KP     13
#define BIG    3.0e38f
#define PADX   1.0e30f

__device__ __forceinline__ int bin_of(float x) {
  int b = (int)((x - XMIN_) * INVBW_);
  b = b < 0 ? 0 : b;
  b = b > NBINS - 1 ? NBINS - 1 : b;
  return b;
}

// device-scope spin barrier; 64 tiny blocks are trivially co-resident
__device__ __forceinline__ void gbar(int* c, int target) {
  __syncthreads();
  if (threadIdx.x == 0) {
    __threadfence();
    atomicAdd(c, 1);
    while (atomicAdd(c, 0) < target) __builtin_amdgcn_s_sleep(2);
    __threadfence();
  }
  __syncthreads();
}

// ---------------- K1: fused counting sort (hist | scan | scatter) ------------
__global__ __launch_bounds__(STHR)
void sort_kernel(const float* __restrict__ p, int* __restrict__ hist,
                 int* __restrict__ cursor, int* __restrict__ cnt,
                 float4* __restrict__ sorted, int n) {
  __shared__ int ssum[STHR];
  const int tid = threadIdx.x;
  const int gid = blockIdx.x * STHR + tid;

  for (int i = gid; i < n; i += SORTB * STHR)
    atomicAdd(&hist[bin_of(p[3 * i])], 1);

  gbar(&cnt[0], SORTB);

  if (blockIdx.x == 0) {
    const int base = tid * (NBINS / STHR);
    int v[NBINS / STHR];
    int sum = 0;
#pragma unroll
    for (int t = 0; t < NBINS / STHR; ++t) { v[t] = hist[base + t]; sum += v[t]; }
    ssum[tid] = sum;
    __syncthreads();
    for (int off = 1; off < STHR; off <<= 1) {
      const int x = (tid >= off) ? ssum[tid - off] : 0;
      __syncthreads();
      ssum[tid] += x;
      __syncthreads();
    }
    int run = (tid > 0) ? ssum[tid - 1] : 0;
#pragma unroll
    for (int t = 0; t < NBINS / STHR; ++t) { cursor[base + t] = run; run += v[t]; }
  }

  gbar(&cnt[1], SORTB);

  for (int i = gid; i < n; i += SORTB * STHR) {
    const float x = p[3 * i], y = p[3 * i + 1], z = p[3 * i + 2];
    const int pos = atomicAdd(&cursor[bin_of(x)], 1);
    sorted[pos] = make_float4(x, y, z, __int_as_float(i));
  }
}

// ---------------- K2: query ---------------------------------------------------
__global__ __launch_bounds__(BLOCK)
void query_kernel(const float4* __restrict__ sv, const float* __restrict__ W,
                  const float* __restrict__ bias, float* __restrict__ out, int n) {
  __shared__ __align__(16) float s_x[CHUNK];
  __shared__ __align__(16) float s_y[CHUNK];
  __shared__ __align__(16) float s_z[CHUNK];
  __shared__ float s_d[BLOCK * KP];
  __shared__ float s_tub[QPB];
  __shared__ float s_tau[QPB];
  __shared__ float s_q[QPB];
  __shared__ float s_cb[2 * MAXCHK];

  const int tid  = threadIdx.x;
  const int sl   = tid & (GL - 1);
  const int ql   = tid >> 4;
  const int t    = blockIdx.x * QPB + ql;
  const int nchk = (n + CHUNK - 1) / CHUNK;
  const int sc   = (blockIdx.x * QPB + QPB / 2) / CHUNK;   // seed chunk

  const float4 me = sv[t];
  const float xi = me.x, yi = me.y, zi = me.z;
  const int orig = __float_as_int(me.w);
  const float W0 = W[0], W1 = W[1], W2 = W[2];

  // chunk x-range table + block query x-range
  if (tid < nchk) {
    const int last = ((tid + 1) * CHUNK < n ? (tid + 1) * CHUNK : n) - 1;
    s_cb[2 * tid]     = sv[tid * CHUNK].x - BWS_;
    s_cb[2 * tid + 1] = sv[last].x + BWS_;
  }
  if (sl == 0) s_q[ql] = xi;
  __syncthreads();
  float xmn = s_q[0], xmx = s_q[0];
#pragma unroll
  for (int k = 1; k < QPB; ++k) { xmn = fminf(xmn, s_q[k]); xmx = fmaxf(xmx, s_q[k]); }

  float qd[KK];
#pragma unroll
  for (int k = 0; k < KK; ++k) qd[k] = BIG;

  // ======== seed chunk: stage + branchless insert ========
#pragma unroll
  for (int j0 = 0; j0 < CHUNK; j0 += BLOCK) {
    const int j = j0 + tid;
    const int pos = sc * CHUNK + j;
    const float4 cc = (pos < n) ? sv[pos] : make_float4(PADX, PADX, PADX, 0.f);
    s_x[j] = cc.x; s_y[j] = cc.y; s_z[j] = cc.z;
  }
  __syncthreads();
#pragma unroll 2
  for (int g = sl; g < CHUNK / 4; g += GL) {
    const int cb = g * 4;
    const float4 X = *(const float4*)&s_x[cb];
    const float4 Y = *(const float4*)&s_y[cb];
    const float4 Z = *(const float4*)&s_z[cb];
    float d2v[4];
    { const float dx = xi - X.x, dy = yi - Y.x, dz = zi - Z.x; d2v[0] = dx*dx + dy*dy + dz*dz; }
    { const float dx = xi - X.y, dy = yi - Y.y, dz = zi - Z.y; d2v[1] = dx*dx + dy*dy + dz*dz; }
    { const float dx = xi - X.z, dy = yi - Y.z, dz = zi - Z.z; d2v[2] = dx*dx + dy*dy + dz*dz; }
    { const float dx = xi - X.w, dy = yi - Y.w, dz = zi - Z.w; d2v[3] = dx*dx + dy*dy + dz*dz; }
#pragma unroll
    for (int e = 0; e < 4; ++e) {
      const float d = d2v[e];
#pragma unroll
      for (int k = KK - 1; k >= 1; --k)
        qd[k] = __builtin_amdgcn_fmed3f(d, qd[k - 1], qd[k]);
      qd[0] = fminf(qd[0], d);
    }
  }

  // ---- merge 16 lists -> tau_ub per query ----
  __syncthreads();
#pragma unroll
  for (int k = 0; k < KK; ++k) s_d[tid * KP + k] = qd[k];
  __syncthreads();
  if (sl == 0) {
    int h[GL];
#pragma unroll
    for (int g = 0; g < GL; ++g) h[g] = 0;
    float tt = 0.f;
    for (int r = 0; r < KK; ++r) {
      float best = 3.4e38f; int bs = 0;
#pragma unroll
      for (int g = 0; g < GL; ++g) {
        const float v = s_d[(tid + g) * KP + h[g]];
        if (v < best) { best = v; bs = g; }
      }
#pragma unroll
      for (int g = 0; g < GL; ++g) h[g] += (bs == g) ? 1 : 0;
      tt = best;
    }
    s_tub[ql] = tt;
  }
  __syncthreads();
  float bt = s_tub[0];
#pragma unroll
  for (int k = 1; k < QPB; ++k) bt = fmaxf(bt, s_tub[k]);

  // ======== scan A: remaining chunks with uniform skip ========
  for (int c = 0; c < nchk; ++c) {
    if (c == sc) continue;
    const float gR = s_cb[2 * c] - xmx;       // chunk entirely right of queries
    const float gL = xmn - s_cb[2 * c + 1];   // chunk entirely left
    const bool skip = (gR > 0.f && gR * gR > bt) || (gL > 0.f && gL * gL > bt);
    if (skip) continue;                        // block-uniform

    __syncthreads();
#pragma unroll
    for (int j0 = 0; j0 < CHUNK; j0 += BLOCK) {
      const int j = j0 + tid;
      const int pos = c * CHUNK + j;
      const float4 cc = (pos < n) ? sv[pos] : make_float4(PADX, PADX, PADX, 0.f);
      s_x[j] = cc.x; s_y[j] = cc.y; s_z[j] = cc.z;
    }
    __syncthreads();
#pragma unroll 2
    for (int g = sl; g < CHUNK / 4; g += GL) {
      const int cb = g * 4;
      const float4 X = *(const float4*)&s_x[cb];
      const float4 Y = *(const float4*)&s_y[cb];
      const float4 Z = *(const float4*)&s_z[cb];
      float d2v[4];
      { const float dx = xi - X.x, dy = yi - Y.x, dz = zi - Z.x; d2v[0] = dx*dx + dy*dy + dz*dz; }
      { const float dx = xi - X.y, dy = yi - Y.y, dz = zi - Z.y; d2v[1] = dx*dx + dy*dy + dz*dz; }
      { const float dx = xi - X.z, dy = yi - Y.z, dz = zi - Z.z; d2v[2] = dx*dx + dy*dy + dz*dz; }
      { const float dx = xi - X.w, dy = yi - Y.w, dz = zi - Z.w; d2v[3] = dx*dx + dy*dy + dz*dz; }
#pragma unroll
      for (int e = 0; e < 4; ++e) {
        const float d = d2v[e];
#pragma unroll
        for (int k = KK - 1; k >= 1; --k)
          qd[k] = __builtin_amdgcn_fmed3f(d, qd[k - 1], qd[k]);
        qd[0] = fminf(qd[0], d);
      }
    }
  }

  // ---- merge 16 lists -> exact tau per query ----
  __syncthreads();
#pragma unroll
  for (int k = 0; k < KK; ++k) s_d[tid * KP + k] = qd[k];
  __syncthreads();
  if (sl == 0) {
    int h[GL];
#pragma unroll
    for (int g = 0; g < GL; ++g) h[g] = 0;
    float tt = 0.f;
    for (int r = 0; r < KK; ++r) {
      float best = 3.4e38f; int bs = 0;
#pragma unroll
      for (int g = 0; g < GL; ++g) {
        const float v = s_d[(tid + g) * KP + h[g]];
        if (v < best) { best = v; bs = g; }
      }
#pragma unroll
      for (int g = 0; g < GL; ++g) h[g] += (bs == g) ? 1 : 0;
      tt = best;
    }
    s_tau[ql] = tt;
  }
  __syncthreads();
  const float tau = s_tau[ql];
  float btB = s_tau[0];
#pragma unroll
  for (int k = 1; k < QPB; ++k) btB = fmaxf(btB, s_tau[k]);

  // ======== scan B: uniform chunk skip + branchless masked accumulate ========
  float acc = 0.f;
  for (int c = 0; c < nchk; ++c) {
    const float gR = s_cb[2 * c] - xmx;
    const float gL = xmn - s_cb[2 * c + 1];
    const bool skip = (gR > 0.f && gR * gR > btB) || (gL > 0.f && gL * gL > btB);
    if (skip) continue;

    __syncthreads();
#pragma unroll
    for (int j0 = 0; j0 < CHUNK; j0 += BLOCK) {
      const int j = j0 + tid;
      const int pos = c * CHUNK + j;
      const float4 cc = (pos < n) ? sv[pos] : make_float4(PADX, PADX, PADX, 0.f);
      s_x[j] = cc.x; s_y[j] = cc.y; s_z[j] = cc.z;
    }
    __syncthreads();
#pragma unroll 2
    for (int g = sl; g < CHUNK / 4; g += GL) {
      const int cb = g * 4;
      const float4 X = *(const float4*)&s_x[cb];
      const float4 Y = *(const float4*)&s_y[cb];
      const float4 Z = *(const float4*)&s_z[cb];
      {
        const float dx = xi - X.x, dy = yi - Y.x, dz = zi - Z.x;
        const float d2 = dx*dx + dy*dy + dz*dz;
        const float w = fmaf(W0, fabsf(dx), fmaf(W1, fabsf(dy), W2 * fabsf(dz)));
        acc += (d2 <= tau) ? w : 0.f;
      }
      {
        const float dx = xi - X.y, dy = yi - Y.y, dz = zi - Z.y;
        const float d2 = dx*dx + dy*dy + dz*dz;
        const float w = fmaf(W0, fabsf(dx), fmaf(W1, fabsf(dy), W2 * fabsf(dz)));
        acc += (d2 <= tau) ? w : 0.f;
      }
      {
        const float dx = xi - X.z, dy = yi - Y.z, dz = zi - Z.z;
        const float d2 = dx*dx + dy*dy + dz*dz;
        const float w = fmaf(W0, fabsf(dx), fmaf(W1, fabsf(dy), W2 * fabsf(dz)));
        acc += (d2 <= tau) ? w : 0.f;
      }
      {
        const float dx = xi - X.w, dy = yi - Y.w, dz = zi - Z.w;
        const float d2 = dx*dx + dy*dy + dz*dz;
        const float w = fmaf(W0, fabsf(dx), fmaf(W1, fabsf(dy), W2 * fabsf(dz)));
        acc += (d2 <= tau) ? w : 0.f;
      }
    }
  }

  // ---- reduce over 16 slice lanes (contiguous in wave), leader writes ----
  acc += __shfl_xor(acc, 1);
  acc += __shfl_xor(acc, 2);
  acc += __shfl_xor(acc, 4);
  acc += __shfl_xor(acc, 8);
  if (sl == 0) {
    const float xw0 = W0 * xi + W1 * yi + W2 * zi;
    // 1 + 11/sqrt(2)
    out[orig] = bias[0] + (xw0 * 8.778174593052022f + 0.5f * acc) * (1.0f / 12.0f);
  }
}

extern "C" void kernel_launch(void* const* d_in, const int* in_sizes, int n_in,
                              void* d_out, int out_size, void* d_ws, size_t ws_size,
                              hipStream_t stream) {
  const float* p  = (const float*)d_in[0];
  const float* W  = (const float*)d_in[1];
  const float* bb = (const float*)d_in[2];
  float* out = (float*)d_out;

  const int n = in_sizes[0] / 3;   // 16384

  // ws layout: hist[2048] @0 | cnt[2] @8192 | cursor[2048] @8256 | sorted @16448
  int*    hist   = (int*)d_ws;
  int*    cnt    = (int*)((char*)d_ws + 8192);
  int*    cursor = (int*)((char*)d_ws + 8256);
  float4* sorted = (float4*)((char*)d_ws + 16448);

  hipMemsetAsync(d_ws, 0, 8256, stream);   // hist + cnt
  sort_kernel<<<SORTB, STHR, 0, stream>>>(p, hist, cursor, cnt, sorted, n);
  query_kernel<<<n / QPB, BLOCK, 0, stream>>>(sorted, W, bb, out, n);
}

// Round 8
// 194.999 us; speedup vs baseline: 2.0761x; 1.1717x over previous
//
#include <hip/hip_runtime.h>
#include <math.h>

// n=16384 Gaussian points in 3D. Exact 12-NN (incl self) per point:
//   out[i] = b + ( (W·p_i)·(1 + 11/sqrt(2)) + 0.5 * sum_{11NN} W·|p_i - p_j| ) / 12
//
// R8: x-bin counting sort (1 fused dispatch), then ONE WAVE PER QUERY (16384
// waves = 8/SIMD, zero LDS):
//   1. seed: 768 consecutive sorted positions around the query, branchless
//      med3 per-lane top-12 (12 coalesced float4 steps).
//   2. u0 = 12th smallest of the 64 LANE MINIMA (12-round shfl knockout).
//      Valid UB of the union 12th: 12 lanes each hold >=1 candidate <= u0.
//      Tight (~union 13-14th), unlike min-of-lane-12ths (~9x too big).
//   3. march right then left, 64 candidates/step, until
//      (x-gap - binwidth)^2 > u0  (wave-uniform break; bins monotone in x).
//   4. exact tau = 12-round destructive shift-merge of the 64 sorted lists.
//   5. phase 2: branchless rescan of the march extent, acc += W·|diff| where
//      d2 <= tau (self adds 0). Wave-reduce, lane 0 writes.
// Exact: every point with d2 <= tau lies inside the march extent (outside
// points have gap^2 > u0 >= tau); tau is the exact union 12th.

#define NBINS  2048
#define XMIN_  (-6.0f)
#define INVBW_ ((float)NBINS / 12.0f)
#define SLACK_ ((12.0f / (float)NBINS) * 1.02f)
#define SORTB  64
#define STHR   256
#define BLOCK  256
#define WPB    4            // waves (queries) per block
#define SEED   768
#define KK     12
#define BIG    3.0e38f
#define PADX   1.0e30f

__device__ __forceinline__ int bin_of(float x) {
  int b = (int)((x - XMIN_) * INVBW_);
  b = b < 0 ? 0 : b;
  b = b > NBINS - 1 ? NBINS - 1 : b;
  return b;
}

// device-scope spin barrier; 64 tiny blocks are trivially co-resident
__device__ __forceinline__ void gbar(int* c, int target) {
  __syncthreads();
  if (threadIdx.x == 0) {
    __threadfence();
    atomicAdd(c, 1);
    while (atomicAdd(c, 0) < target) __builtin_amdgcn_s_sleep(2);
    __threadfence();
  }
  __syncthreads();
}

// ---------------- K1: fused counting sort (hist | scan | scatter) ------------
__global__ __launch_bounds__(STHR)
void sort_kernel(const float* __restrict__ p, int* __restrict__ hist,
                 int* __restrict__ cursor, int* __restrict__ cnt,
                 float4* __restrict__ sorted, int n) {
  __shared__ int ssum[STHR];
  const int tid = threadIdx.x;
  const int gid = blockIdx.x * STHR + tid;

  for (int i = gid; i < n; i += SORTB * STHR)
    atomicAdd(&hist[bin_of(p[3 * i])], 1);

  gbar(&cnt[0], SORTB);

  if (blockIdx.x == 0) {
    const int base = tid * (NBINS / STHR);
    int v[NBINS / STHR];
    int sum = 0;
#pragma unroll
    for (int t = 0; t < NBINS / STHR; ++t) { v[t] = hist[base + t]; sum += v[t]; }
    ssum[tid] = sum;
    __syncthreads();
    for (int off = 1; off < STHR; off <<= 1) {
      const int x = (tid >= off) ? ssum[tid - off] : 0;
      __syncthreads();
      ssum[tid] += x;
      __syncthreads();
    }
    int run = (tid > 0) ? ssum[tid - 1] : 0;
#pragma unroll
    for (int t = 0; t < NBINS / STHR; ++t) { cursor[base + t] = run; run += v[t]; }
  }

  gbar(&cnt[1], SORTB);

  for (int i = gid; i < n; i += SORTB * STHR) {
    const float x = p[3 * i], y = p[3 * i + 1], z = p[3 * i + 2];
    const int pos = atomicAdd(&cursor[bin_of(x)], 1);
    sorted[pos] = make_float4(x, y, z, __int_as_float(i));
  }
}

// ---------------- K2: query (one wave per query, no LDS) ----------------------
__global__ __launch_bounds__(BLOCK)
void query_kernel(const float4* __restrict__ sv, const float* __restrict__ W,
                  const float* __restrict__ bias, float* __restrict__ out, int n) {
  const int lane = threadIdx.x & 63;
  const int t    = blockIdx.x * WPB + (threadIdx.x >> 6);   // query position

  const float4 me = sv[t];
  const float xi = me.x, yi = me.y, zi = me.z;
  const int orig = __float_as_int(me.w);
  const float W0 = W[0], W1 = W[1], W2 = W[2];

  float qd[KK];
#pragma unroll
  for (int k = 0; k < KK; ++k) qd[k] = BIG;

  int lo = t - SEED / 2;
  lo = lo < 0 ? 0 : lo;
  lo = lo > n - SEED ? n - SEED : lo;

  // ---- 1. seed fill: 12 coalesced steps, branchless insert ----
#pragma unroll
  for (int s = 0; s < SEED / 64; ++s) {
    const float4 c = sv[lo + s * 64 + lane];
    const float dx = xi - c.x, dy = yi - c.y, dz = zi - c.z;
    const float d2 = fmaf(dx, dx, fmaf(dy, dy, dz * dz));
#pragma unroll
    for (int k = KK - 1; k >= 1; --k)
      qd[k] = __builtin_amdgcn_fmed3f(d2, qd[k - 1], qd[k]);
    qd[0] = fminf(qd[0], d2);
  }

  // ---- 2. u0 = 12th smallest of the 64 lane minima (knockout) ----
  float u;
  {
    float v = qd[0];
    float m = BIG;
#pragma unroll
    for (int r = 0; r < KK; ++r) {
      m = v;
#pragma unroll
      for (int o = 1; o < 64; o <<= 1) m = fminf(m, __shfl_xor(m, o));
      v = (v == m) ? BIG : v;
    }
    u = m;
  }

  // ---- 3a. right march ----
  int rp = lo + SEED;
  while (rp < n) {
    const int pos = rp + lane;
    const bool vld = pos < n;
    const float4 c = vld ? sv[pos] : make_float4(PADX, PADX, PADX, 0.f);
    const float dx = xi - c.x, dy = yi - c.y, dz = zi - c.z;
    const float d2 = vld ? fmaf(dx, dx, fmaf(dy, dy, dz * dz)) : BIG;
#pragma unroll
    for (int k = KK - 1; k >= 1; --k)
      qd[k] = __builtin_amdgcn_fmed3f(d2, qd[k - 1], qd[k]);
    qd[0] = fminf(qd[0], d2);
    const float xf = __shfl(c.x, 63);       // rightmost scanned x (wave-uniform)
    rp += 64;
    const float gap = xf - SLACK_ - xi;     // unscanned right: x >= xf - BW
    if (gap > 0.f && gap * gap > u) break;
  }

  // ---- 3b. left march ----
  int lp = lo - 1;
  while (lp >= 0) {
    const int pos = lp - lane;
    const bool vld = pos >= 0;
    const float4 c = vld ? sv[pos] : make_float4(-PADX, -PADX, -PADX, 0.f);
    const float dx = xi - c.x, dy = yi - c.y, dz = zi - c.z;
    const float d2 = vld ? fmaf(dx, dx, fmaf(dy, dy, dz * dz)) : BIG;
#pragma unroll
    for (int k = KK - 1; k >= 1; --k)
      qd[k] = __builtin_amdgcn_fmed3f(d2, qd[k - 1], qd[k]);
    qd[0] = fminf(qd[0], d2);
    const float xf = __shfl(c.x, 63);       // leftmost scanned x
    lp -= 64;
    const float gap = xi - SLACK_ - xf;     // unscanned left: x <= xf + BW
    if (gap > 0.f && gap * gap > u) break;
  }

  // ---- 4. exact tau: 12-round destructive shift-merge across lanes ----
  float tau;
  {
    float m = 0.f;
#pragma unroll
    for (int r = 0; r < KK; ++r) {
      m = qd[0];
#pragma unroll
      for (int o = 1; o < 64; o <<= 1) m = fminf(m, __shfl_xor(m, o));
      if (qd[0] == m) {
#pragma unroll
        for (int k = 0; k < KK - 1; ++k) qd[k] = qd[k + 1];
        qd[KK - 1] = BIG;
      }
    }
    tau = m;
  }

  // ---- 5. phase 2: branchless rescan of the march extent ----
  int Lo = lp + 1; Lo = Lo < 0 ? 0 : Lo;
  int Hi = rp;     Hi = Hi > n ? n : Hi;
  float acc = 0.f;
  for (int pos = Lo + lane; pos < Hi; pos += 64) {
    const float4 c = sv[pos];
    const float dx = xi - c.x, dy = yi - c.y, dz = zi - c.z;
    const float d2 = fmaf(dx, dx, fmaf(dy, dy, dz * dz));
    const float w  = fmaf(W0, fabsf(dx), fmaf(W1, fabsf(dy), W2 * fabsf(dz)));
    acc += (d2 <= tau) ? w : 0.f;
  }
#pragma unroll
  for (int o = 1; o < 64; o <<= 1) acc += __shfl_xor(acc, o);

  if (lane == 0) {
    const float xw0 = W0 * xi + W1 * yi + W2 * zi;
    // 1 + 11/sqrt(2)
    out[orig] = bias[0] + (xw0 * 8.778174593052022f + 0.5f * acc) * (1.0f / 12.0f);
  }
}

extern "C" void kernel_launch(void* const* d_in, const int* in_sizes, int n_in,
                              void* d_out, int out_size, void* d_ws, size_t ws_size,
                              hipStream_t stream) {
  const float* p  = (const float*)d_in[0];
  const float* W  = (const float*)d_in[1];
  const float* bb = (const float*)d_in[2];
  float* out = (float*)d_out;

  const int n = in_sizes[0] / 3;   // 16384

  // ws layout: hist[2048] @0 | cnt[2] @8192 | cursor[2048] @8256 | sorted @16448
  int*    hist   = (int*)d_ws;
  int*    cnt    = (int*)((char*)d_ws + 8192);
  int*    cursor = (int*)((char*)d_ws + 8256);
  float4* sorted = (float4*)((char*)d_ws + 16448);

  hipMemsetAsync(d_ws, 0, 8256, stream);   // hist + cnt
  sort_kernel<<<SORTB, STHR, 0, stream>>>(p, hist, cursor, cnt, sorted, n);
  query_kernel<<<n / WPB, BLOCK, 0, stream>>>(sorted, W, bb, out, n);
}